// Round 7
// baseline (151.381 us; speedup 1.0000x reference)
//
#include <hip/hip_runtime.h>
#include <math.h>

#define NN 8192
typedef unsigned int u32;

__device__ __forceinline__ u32 dot4u(u32 a, u32 b, u32 c) {
#if __has_builtin(__builtin_amdgcn_udot4)
  return __builtin_amdgcn_udot4(a, b, c, false);
#else
  c += (a & 0xffu) * (b & 0xffu);
  c += ((a >> 8) & 0xffu) * ((b >> 8) & 0xffu);
  c += ((a >> 16) & 0xffu) * ((b >> 16) & 0xffu);
  c += (a >> 24) * (b >> 24);
  return c;
#endif
}

// ---------------------------------------------------------------------------
// Pass 1: h0 = adj_f32 @ [dfp,dts] (exact f32); emit adj8 = round(adj*255);
// fused MLP_l0 -> cur0 + per-block feature-max partials; zeroes done-counter.
// 2048 blocks x 256 thr (4 waves). WAVE OWNS 1 ROW across full k (single
// butterfly, no cross-wave reduce). Chunk = 512 floats; x loads issued FIRST
// so waiting on them keeps the adj prefetch (issued after) in flight
// (vmcnt retires in order: waiting for an OLDER load leaves YOUNGER
// prefetches outstanding). 8 waves/SIMD for latency hiding.
// ---------------------------------------------------------------------------
__global__ __launch_bounds__(256, 8) void pass1_kernel(
    const float* __restrict__ adj, u32* __restrict__ adj8,
    const float* __restrict__ dfp, const float* __restrict__ dts,
    const float* __restrict__ W1, const float* __restrict__ b1,
    const float* __restrict__ W2, const float* __restrict__ b2,
    float* __restrict__ cur, float* __restrict__ partial,
    u32* __restrict__ cnt) {
  const int tid = threadIdx.x, wave = tid >> 6, lane = tid & 63;
  const int row = blockIdx.x * 4 + wave;
  __shared__ float wmax[4][8];
  if (blockIdx.x == 0 && tid == 0) cnt[0] = 0;  // reset done-counter

  const float* rowp = adj + (size_t)row * NN;
  u32* qp = adj8 + (size_t)row * 2048;

  float acc0 = 0.f, acc1 = 0.f;
  float4 A0 = *(const float4*)(rowp + 4 * lane);
  float4 A1 = *(const float4*)(rowp + 256 + 4 * lane);
  for (int c = 0; c < 16; ++c) {
    const int kb = 512 * c;
    // x loads FIRST (older in vmcnt order than the prefetch below)
    float4 xp0 = *(const float4*)(dfp + kb + 4 * lane);
    float4 xp1 = *(const float4*)(dfp + kb + 256 + 4 * lane);
    float4 xs0 = *(const float4*)(dts + kb + 4 * lane);
    float4 xs1 = *(const float4*)(dts + kb + 256 + 4 * lane);
    float4 B0, B1;
    if (c < 15) {  // prefetch next chunk (younger: stays in flight)
      B0 = *(const float4*)(rowp + kb + 512 + 4 * lane);
      B1 = *(const float4*)(rowp + kb + 768 + 4 * lane);
    } else {
      B0 = A0; B1 = A1;
    }
    acc0 = fmaf(A0.x, xp0.x, acc0); acc0 = fmaf(A0.y, xp0.y, acc0);
    acc0 = fmaf(A0.z, xp0.z, acc0); acc0 = fmaf(A0.w, xp0.w, acc0);
    acc0 = fmaf(A1.x, xp1.x, acc0); acc0 = fmaf(A1.y, xp1.y, acc0);
    acc0 = fmaf(A1.z, xp1.z, acc0); acc0 = fmaf(A1.w, xp1.w, acc0);
    acc1 = fmaf(A0.x, xs0.x, acc1); acc1 = fmaf(A0.y, xs0.y, acc1);
    acc1 = fmaf(A0.z, xs0.z, acc1); acc1 = fmaf(A0.w, xs0.w, acc1);
    acc1 = fmaf(A1.x, xs1.x, acc1); acc1 = fmaf(A1.y, xs1.y, acc1);
    acc1 = fmaf(A1.z, xs1.z, acc1); acc1 = fmaf(A1.w, xs1.w, acc1);
    {
      u32 q0 = (u32)fmaf(A0.x, 255.f, 0.5f);
      u32 q1 = (u32)fmaf(A0.y, 255.f, 0.5f);
      u32 q2 = (u32)fmaf(A0.z, 255.f, 0.5f);
      u32 q3 = (u32)fmaf(A0.w, 255.f, 0.5f);
      qp[128 * c + lane] = q0 | (q1 << 8) | (q2 << 16) | (q3 << 24);
      q0 = (u32)fmaf(A1.x, 255.f, 0.5f);
      q1 = (u32)fmaf(A1.y, 255.f, 0.5f);
      q2 = (u32)fmaf(A1.z, 255.f, 0.5f);
      q3 = (u32)fmaf(A1.w, 255.f, 0.5f);
      qp[128 * c + 64 + lane] = q0 | (q1 << 8) | (q2 << 16) | (q3 << 24);
    }
    A0 = B0; A1 = B1;
  }
  // full-wave butterfly: every lane gets the complete row sums
  for (int off = 32; off; off >>= 1) {
    acc0 += __shfl_xor(acc0, off, 64);
    acc1 += __shfl_xor(acc1, off, 64);
  }
  // fused MLP_l0 for this wave's row
  const int j = lane & 7;
  float z = fmaf(acc0, W1[j], fmaf(acc1, W1[8 + j], b1[j]));
  z = fmaxf(z, 0.f);
  float o = b2[j];
#pragma unroll
  for (int jj = 0; jj < 8; ++jj)
    o = fmaf(__shfl(z, jj, 64), W2[jj * 8 + j], o);
  float val = fmaxf(o, 0.f);
  if (lane < 8) {
    cur[(size_t)row * 8 + j] = val;
    wmax[wave][j] = val;
  }
  __syncthreads();
  if (tid < 8)
    partial[blockIdx.x * 8 + tid] = fmaxf(fmaxf(wmax[0][tid], wmax[1][tid]),
                                          fmaxf(wmax[2][tid], wmax[3][tid]));
}

// ---------------------------------------------------------------------------
// Passes 2/3: h = (adj8/255) @ x via unsigned udot4 (exact i32 accumulation).
// x quantized per-feature to u8, staged feature-major in 64-KiB LDS
// (2 blocks/CU). 512 blocks x 512 thr; wave owns 2 rows across full k.
// Chunk = 1024 bytes/row (uint4/lane), prefetch depth 2 (LDS is lgkmcnt, so
// no vmcnt hazard here). HEADS=0: fused MLP_l1 + partials. HEADS=1: pol/val
// heads + LAST-BLOCK fused reduce+finalize (softmax + value normalize).
// ---------------------------------------------------------------------------
template <int HEADS>
__global__ __launch_bounds__(512, 4) void pass23_kernel(
    const u32* __restrict__ adj8, const float* __restrict__ x,
    const float* __restrict__ partial, int nprod,
    const float* __restrict__ W1, const float* __restrict__ b1,
    const float* __restrict__ W2, const float* __restrict__ b2,
    const float* __restrict__ W1v, const float* __restrict__ b1v,
    const float* __restrict__ W2v, const float* __restrict__ b2v,
    float* __restrict__ out0, float* __restrict__ out1,
    float* __restrict__ partial_out, u32* __restrict__ cnt) {
  __shared__ u32 sxT[8 * 2048];  // 64 KiB, feature-major: dword p = rows 4p..4p+3
  __shared__ float redM[8][8];
  __shared__ float sqs[8], sds[8];
  __shared__ float wmax[8][8];
  __shared__ float sa[8], sb[8], sc[4];
  __shared__ int lastFlag;
  const int tid = threadIdx.x, wave = tid >> 6, lane = tid & 63;
  const int row0 = blockIdx.x * 16 + wave * 2;

  const u32* r0p = adj8 + (size_t)row0 * 2048;
  const u32* r1p = adj8 + (size_t)(row0 + 1) * 2048;
  // issue first two adj chunks early (overlap with scales + staging)
  uint4 A[2], Bp[2];
  A[0] = *(const uint4*)(r0p + 4 * lane);
  A[1] = *(const uint4*)(r1p + 4 * lane);
  Bp[0] = *(const uint4*)(r0p + 256 + 4 * lane);
  Bp[1] = *(const uint4*)(r1p + 256 + 4 * lane);

  // --- per-feature max from producer partials -> quant/dequant scales ---
  float pm[8] = {0.f, 0.f, 0.f, 0.f, 0.f, 0.f, 0.f, 0.f};
  for (int p = tid; p < nprod; p += 512) {
    float4 a = *(const float4*)(partial + p * 8);
    float4 b = *(const float4*)(partial + p * 8 + 4);
    pm[0] = fmaxf(pm[0], a.x); pm[1] = fmaxf(pm[1], a.y);
    pm[2] = fmaxf(pm[2], a.z); pm[3] = fmaxf(pm[3], a.w);
    pm[4] = fmaxf(pm[4], b.x); pm[5] = fmaxf(pm[5], b.y);
    pm[6] = fmaxf(pm[6], b.z); pm[7] = fmaxf(pm[7], b.w);
  }
  for (int off = 32; off; off >>= 1)
#pragma unroll
    for (int j = 0; j < 8; ++j) pm[j] = fmaxf(pm[j], __shfl_xor(pm[j], off, 64));
  if (lane == 0)
#pragma unroll
    for (int j = 0; j < 8; ++j) redM[wave][j] = pm[j];
  __syncthreads();
  if (tid < 8) {
    float m2 = 0.f;
#pragma unroll
    for (int w = 0; w < 8; ++w) m2 = fmaxf(m2, redM[w][tid]);
    m2 = fmaxf(m2, 1e-20f);
    sqs[tid] = 255.f / m2;
    sds[tid] = m2 / 65025.f;
  }
  __syncthreads();

  // --- stage x feature-major: thread packs 4 consecutive rows per dword ---
  float qs[8];
#pragma unroll
  for (int j = 0; j < 8; ++j) qs[j] = sqs[j];
  for (int gi = 0; gi < 4; ++gi) {
    const int p = gi * 512 + tid;
    u32 pk[8] = {0, 0, 0, 0, 0, 0, 0, 0};
#pragma unroll
    for (int m = 0; m < 4; ++m) {
      const float* xr = x + (size_t)(4 * p + m) * 8;
      float4 a = *(const float4*)xr;
      float4 b = *(const float4*)(xr + 4);
      const float e[8] = {a.x, a.y, a.z, a.w, b.x, b.y, b.z, b.w};
#pragma unroll
      for (int j = 0; j < 8; ++j)
        pk[j] |= ((u32)fmaf(e[j], qs[j], 0.5f)) << (8 * m);
    }
#pragma unroll
    for (int j = 0; j < 8; ++j) sxT[j * 2048 + p] = pk[j];
  }
  __syncthreads();

  // --- main loop: 8 chunks of 1024 k, pure udot4, depth-2 prefetch ---
  u32 acc[2][8] = {};
  for (int c = 0; c < 8; ++c) {
    uint4 C[2];
    if (c + 2 < 8) {
      C[0] = *(const uint4*)(r0p + 256 * (c + 2) + 4 * lane);
      C[1] = *(const uint4*)(r1p + 256 * (c + 2) + 4 * lane);
    } else {
      C[0] = A[0];
      C[1] = A[1];
    }
    uint4 xq[8];
#pragma unroll
    for (int jj = 0; jj < 8; ++jj)
      xq[jj] = ((const uint4*)sxT)[jj * 512 + 64 * c + lane];
#pragma unroll
    for (int r = 0; r < 2; ++r) {
      const uint4 a4 = A[r];
#pragma unroll
      for (int jj = 0; jj < 8; ++jj) {
        u32 cc = acc[r][jj];
        cc = dot4u(a4.x, xq[jj].x, cc);
        cc = dot4u(a4.y, xq[jj].y, cc);
        cc = dot4u(a4.z, xq[jj].z, cc);
        cc = dot4u(a4.w, xq[jj].w, cc);
        acc[r][jj] = cc;
      }
    }
    A[0] = Bp[0]; A[1] = Bp[1];
    Bp[0] = C[0]; Bp[1] = C[1];
  }
  // single butterfly -> full sums in all lanes; dequantize
#pragma unroll
  for (int r = 0; r < 2; ++r)
#pragma unroll
    for (int jj = 0; jj < 8; ++jj)
      for (int off = 32; off; off >>= 1)
        acc[r][jj] += (u32)__shfl_xor((int)acc[r][jj], off, 64);
  float h[2][8];
#pragma unroll
  for (int r = 0; r < 2; ++r)
#pragma unroll
    for (int jj = 0; jj < 8; ++jj) h[r][jj] = (float)acc[r][jj] * sds[jj];

  if (HEADS == 0) {
    const int j = lane & 7;
    float mxv = 0.f;
#pragma unroll
    for (int r = 0; r < 2; ++r) {
      float z = b1[j];
#pragma unroll
      for (int d = 0; d < 8; ++d) z = fmaf(h[r][d], W1[d * 8 + j], z);
      z = fmaxf(z, 0.f);
      float o = b2[j];
#pragma unroll
      for (int jj = 0; jj < 8; ++jj)
        o = fmaf(__shfl(z, jj, 64), W2[jj * 8 + j], o);
      float val = fmaxf(o, 0.f);
      if (lane < 8) out0[(size_t)(row0 + r) * 8 + j] = val;
      mxv = fmaxf(mxv, val);
    }
    if (lane < 8) wmax[wave][lane] = mxv;
    __syncthreads();
    if (tid < 8) {
      float m2 = 0.f;
#pragma unroll
      for (int w = 0; w < 8; ++w) m2 = fmaxf(m2, wmax[w][tid]);
      partial_out[blockIdx.x * 8 + tid] = m2;
    }
  } else {
    if (lane == 0) {
#pragma unroll
      for (int r = 0; r < 2; ++r) {
        float zp = b1[0], zv = b1v[0];
#pragma unroll
        for (int d = 0; d < 8; ++d) {
          zp = fmaf(h[r][d], W1[d], zp);
          zv = fmaf(h[r][d], W1v[d], zv);
        }
        zp = fmaxf(zp, 0.f);
        zv = fmaxf(zv, 0.f);
        out0[row0 + r] = fmaf(zp, W2[0], b2[0]);
        out1[row0 + r] = fmaf(zv, W2v[0], b2v[0]);
      }
    }
    // ---- last-block fused reduce + finalize ----
    __syncthreads();  // all logits/value writes of this block issued & acked
    if (tid == 0) {
      __threadfence();  // release this block's writes device-wide
      u32 old = atomicAdd(cnt, 1);
      lastFlag = (old == (u32)(gridDim.x - 1)) ? 1 : 0;
    }
    __syncthreads();
    if (lastFlag) {
      __threadfence();  // acquire other blocks' writes
      float lv[16], vv[16];
#pragma unroll
      for (int i = 0; i < 4; ++i) {
        float4 a = *(const float4*)(out0 + tid * 16 + 4 * i);
        float4 b = *(const float4*)(out1 + tid * 16 + 4 * i);
        lv[4 * i] = a.x; lv[4 * i + 1] = a.y; lv[4 * i + 2] = a.z; lv[4 * i + 3] = a.w;
        vv[4 * i] = b.x; vv[4 * i + 1] = b.y; vv[4 * i + 2] = b.z; vv[4 * i + 3] = b.w;
      }
      float m = -3.4e38f, s = 0.f;
#pragma unroll
      for (int i = 0; i < 16; ++i) {
        m = fmaxf(m, lv[i]);
        s += vv[i];
      }
      for (int off = 32; off; off >>= 1) {
        m = fmaxf(m, __shfl_xor(m, off, 64));
        s += __shfl_xor(s, off, 64);
      }
      if (lane == 0) { sa[wave] = m; sb[wave] = s; }
      __syncthreads();
      if (tid == 0) {
        float mm = sa[0], ss = sb[0];
        for (int i = 1; i < 8; ++i) { mm = fmaxf(mm, sa[i]); ss += sb[i]; }
        sc[0] = mm; sc[1] = ss * (1.f / NN);
      }
      __syncthreads();
      m = sc[0];
      const float mean = sc[1];
      float e = 0.f, v2 = 0.f;
#pragma unroll
      for (int i = 0; i < 16; ++i) {
        e += expf(lv[i] - m);
        float d = vv[i] - mean;
        v2 = fmaf(d, d, v2);
      }
      for (int off = 32; off; off >>= 1) {
        e += __shfl_xor(e, off, 64);
        v2 += __shfl_xor(v2, off, 64);
      }
      if (lane == 0) { sa[wave] = e; sb[wave] = v2; }
      __syncthreads();
      if (tid == 0) {
        float ee = sa[0], vvv = sb[0];
        for (int i = 1; i < 8; ++i) { ee += sa[i]; vvv += sb[i]; }
        sc[2] = 1.f / ee;
        sc[3] = 1.f / sqrtf(vvv * (1.f / NN) + 1e-10f);
      }
      __syncthreads();
      const float inv_e = sc[2], inv_std = sc[3];
#pragma unroll
      for (int i = 0; i < 4; ++i) {
        float4 po, nv;
        po.x = expf(lv[4 * i] - m) * inv_e;
        po.y = expf(lv[4 * i + 1] - m) * inv_e;
        po.z = expf(lv[4 * i + 2] - m) * inv_e;
        po.w = expf(lv[4 * i + 3] - m) * inv_e;
        nv.x = (vv[4 * i] - mean) * inv_std;
        nv.y = (vv[4 * i + 1] - mean) * inv_std;
        nv.z = (vv[4 * i + 2] - mean) * inv_std;
        nv.w = (vv[4 * i + 3] - mean) * inv_std;
        *(float4*)(out0 + tid * 16 + 4 * i) = po;
        *(float4*)(out1 + tid * 16 + 4 * i) = nv;
      }
    }
  }
}

// ---------------------------------------------------------------------------
extern "C" void kernel_launch(void* const* d_in, const int* in_sizes, int n_in,
                              void* d_out, int out_size, void* d_ws,
                              size_t ws_size, hipStream_t stream) {
  const float* adj = (const float*)d_in[0];
  const float* dfp = (const float*)d_in[1];
  const float* dts = (const float*)d_in[2];
  const float* W1_l0 = (const float*)d_in[3];
  const float* b1_l0 = (const float*)d_in[4];
  const float* W2_l0 = (const float*)d_in[5];
  const float* b2_l0 = (const float*)d_in[6];
  const float* W1_l1 = (const float*)d_in[7];
  const float* b1_l1 = (const float*)d_in[8];
  const float* W2_l1 = (const float*)d_in[9];
  const float* b2_l1 = (const float*)d_in[10];
  const float* W1_pol = (const float*)d_in[11];
  const float* b1_pol = (const float*)d_in[12];
  const float* W2_pol = (const float*)d_in[13];
  const float* b2_pol = (const float*)d_in[14];
  const float* W1_val = (const float*)d_in[15];
  const float* b1_val = (const float*)d_in[16];
  const float* W2_val = (const float*)d_in[17];
  const float* b2_val = (const float*)d_in[18];

  char* base = (char*)d_ws;
  u32* adj8 = (u32*)base;                                   // 64 MiB
  float* curA = (float*)(base + (size_t)NN * NN);           // [N][8]
  float* curB = curA + NN * 8;                              // [N][8]
  float* partialA = curB + NN * 8;                          // [2048][8]
  float* partialB = partialA + 2048 * 8;                    // [512][8]
  u32* cnt = (u32*)(partialB + 512 * 8);                    // [1]
  float* logits = (float*)d_out;
  float* value = logits + NN;

  pass1_kernel<<<2048, 256, 0, stream>>>(adj, adj8, dfp, dts, W1_l0, b1_l0,
                                         W2_l0, b2_l0, curA, partialA, cnt);
  pass23_kernel<0><<<512, 512, 0, stream>>>(
      adj8, curA, partialA, 2048, W1_l1, b1_l1, W2_l1, b2_l1, W1_l1, b1_l1,
      W2_l1, b2_l1, curB, curB, partialB, cnt);
  pass23_kernel<1><<<512, 512, 0, stream>>>(
      adj8, curB, partialB, 512, W1_pol, b1_pol, W2_pol, b2_pol, W1_val,
      b1_val, W2_val, b2_val, logits, value, partialB, cnt);
}